// Round 5
// baseline (485.966 us; speedup 1.0000x reference)
//
#include <hip/hip_runtime.h>
#include <hip/hip_bf16.h>
#include <stdint.h>

typedef __bf16 bf16x8 __attribute__((ext_vector_type(8)));
typedef float f32x4 __attribute__((ext_vector_type(4)));

#define LOG2E 1.4426950408889634f
#define AS1 __attribute__((address_space(1)))
#define AS3 __attribute__((address_space(3)))

// ---------------- prep: build indices from batch_sizes ----------------
__global__ void prep_kernel(const int* __restrict__ bs, int T,
                            const int* __restrict__ sentences,
                            int* __restrict__ hdr, float* __restrict__ fhdr,
                            int* __restrict__ row_ctx, int* __restrict__ row_tok) {
    __shared__ int off[1025];
    if (threadIdx.x == 0) {
        int acc = 0; off[0] = 0;
        for (int t = 0; t < T; ++t) { acc += bs[t]; off[t + 1] = acc; }
    }
    __syncthreads();
    const int total = off[T];
    const int Nf = total - off[1];
    const int Nb = total - off[2];
    for (int t = 1; t < T; ++t) {
        int start = off[t] - off[1];
        int cnt = off[t + 1] - off[t];
        for (int p = threadIdx.x; p < cnt; p += blockDim.x) {
            row_ctx[start + p] = off[t - 1] + p;
            row_tok[start + p] = sentences[off[t] + p];
        }
    }
    for (int i = 1; i < T - 1; ++i) {
        int start = Nf + off[i + 1] - off[2];
        int cnt = off[i + 2] - off[i + 1];
        for (int p = threadIdx.x; p < cnt; p += blockDim.x) {
            row_ctx[start + p] = off[i + 1] + p;
            row_tok[start + p] = sentences[off[i] + p];
        }
    }
    if (threadIdx.x == 0) {
        hdr[0] = Nf + Nb;
        hdr[1] = Nf;
        int bs0 = off[1];
        int bsl = off[T] - off[T - 1];
        fhdr[0] = (float)(2 * total - bs0 - bsl);
    }
}

// ---------------- W f32 -> bf16 ----------------
__global__ void wconv_kernel(const float* __restrict__ W,
                             __hip_bfloat16* __restrict__ Wb, long n4) {
    long i = (long)blockIdx.x * blockDim.x + threadIdx.x;
    if (i >= n4) return;
    float4 v = ((const float4*)W)[i];
    __hip_bfloat16 a0 = __float2bfloat16(v.x), a1 = __float2bfloat16(v.y);
    __hip_bfloat16 a2 = __float2bfloat16(v.z), a3 = __float2bfloat16(v.w);
    ushort4 pk;
    pk.x = *(unsigned short*)&a0; pk.y = *(unsigned short*)&a1;
    pk.z = *(unsigned short*)&a2; pk.w = *(unsigned short*)&a3;
    ((ushort4*)Wb)[i] = pk;
}

// ---------------- gather packed context rows -> bf16, zero S ----------------
__global__ void gather_kernel(const float* __restrict__ hs,
                              const int* __restrict__ row_ctx,
                              const int* __restrict__ hdr,
                              __hip_bfloat16* __restrict__ Hc,
                              float* __restrict__ S, int D2, int D) {
    const int m = blockIdx.x;
    const int M = hdr[0], Nf = hdr[1];
    if (threadIdx.x == 0) S[m] = 0.f;
    ushort4* dst = (ushort4*)(Hc + (size_t)m * D);
    if (m >= M) {
        ushort4 z; z.x = z.y = z.z = z.w = 0;
        for (int i = threadIdx.x; i < D / 4; i += blockDim.x) dst[i] = z;
        return;
    }
    const int ctx = row_ctx[m];
    const float4* src = (const float4*)(hs + (size_t)ctx * D2 + (m < Nf ? 0 : D));
    for (int i = threadIdx.x; i < D / 4; i += blockDim.x) {
        float4 v = src[i];
        __hip_bfloat16 a0 = __float2bfloat16(v.x), a1 = __float2bfloat16(v.y);
        __hip_bfloat16 a2 = __float2bfloat16(v.z), a3 = __float2bfloat16(v.w);
        ushort4 pk;
        pk.x = *(unsigned short*)&a0; pk.y = *(unsigned short*)&a1;
        pk.z = *(unsigned short*)&a2; pk.w = *(unsigned short*)&a3;
        dst[i] = pk;
    }
}

// ---------------- main 256x256 / BK=64 / 8-wave GEMM + sum-exp ----------------
// LDS layout (verified conflict-free r2-r4): unit u (k-quarter) at u*8KB;
// fragment reads are contiguous 512B wave segments.
// Schedule fix vs r4: only TWO barriers per K-tile (the two correctness-
// required staging-visibility points), and all ds_reads issue >=1 MFMA
// cluster ahead of consumption so the compiler's fine-grained lgkmcnt drains
// them under MFMA. vmcnt(4) gate arithmetic unchanged (verified r3/r4).
__global__ __launch_bounds__(512, 2)
void gemm_lse_256(const __hip_bfloat16* __restrict__ A,
                  const __hip_bfloat16* __restrict__ B,
                  const float* __restrict__ fb,
                  const float* __restrict__ bb,
                  float* __restrict__ S,
                  const int* __restrict__ hdr,
                  int K, int MT) {
    const int M = hdr[0], Nf = hdr[1];

    // XCD-aware bijective swizzle (m204), bm-fastest (r2: FETCH -48%).
    const int nwg = gridDim.x, orig = blockIdx.x;
    const int q = nwg >> 3, rr = nwg & 7;
    const int xcd = orig & 7, i8 = orig >> 3;
    const int wgid = (xcd < rr ? xcd * (q + 1) : rr * (q + 1) + (xcd - rr) * q) + i8;
    const int bm = wgid % MT, bn = wgid / MT;
    if (bm * 256 >= M) return;

    __shared__ __align__(16) char lds[2][2][32768];   // [buf][A/B][4 units x 8KB]

    const int tid = threadIdx.x, lane = tid & 63, wid = tid >> 6;
    const int wm = wid >> 2, wn = wid & 3;             // 2 x 4 waves

    f32x4 acc[8][4];
#pragma unroll
    for (int i = 0; i < 8; ++i)
#pragma unroll
        for (int j = 0; j < 4; ++j) acc[i][j] = (f32x4)0.f;

    const int Kb = K * 2;
    const char* gA = (const char*)A + (size_t)bm * 256 * Kb;
    const char* gB = (const char*)B + (size_t)bn * 256 * Kb;

    // staging geometry (verified r4): thread -> (row, khalf), LDS dest linear
    const int srB  = ((((tid >> 5) << 4) | (tid & 15))) * Kb;
    const int shh  = ((tid >> 4) & 1) << 4;
    const int sdst = tid << 4;
    const char* sAg = gA + srB + shh;   // fixed per-thread global bases
    const char* sBg = gB + srB + shh;

    // fragment-read offsets (verified r4): contiguous 512B wave segments
    const int ll   = (((lane >> 4) & 1) << 8) | ((lane & 15) << 4);
    const int ksu  = ((lane >> 5) & 1) << 13;
    const int aoff = ksu + (wm << 12) + ll;   // + KS*16384 + MH*2048 + frag*512
    const int boff = ksu + (wn << 11) + ll;   // + KS*16384 + frag*512

#define STAGEU(nbuf, u, t) do {                                               \
    const int _go = (t) * 128 + ((u) << 5);                                   \
    __builtin_amdgcn_global_load_lds(                                         \
        (const AS1 uint32_t*)(sAg + _go),                                     \
        (AS3 uint32_t*)(&lds[nbuf][0][0] + ((u) << 13) + sdst), 16, 0, 0);    \
    __builtin_amdgcn_global_load_lds(                                         \
        (const AS1 uint32_t*)(sBg + _go),                                     \
        (AS3 uint32_t*)(&lds[nbuf][1][0] + ((u) << 13) + sdst), 16, 0, 0);    \
} while (0)

#define LOAD4(dst, base, off) do {                                            \
    _Pragma("unroll")                                                         \
    for (int _f = 0; _f < 4; ++_f)                                            \
        dst[_f] = *(const bf16x8*)((base) + (off) + _f * 512);                \
} while (0)

#define CL16(av, bv, MH) do {                                                 \
    __builtin_amdgcn_s_setprio(1);                                            \
    _Pragma("unroll")                                                         \
    for (int _i = 0; _i < 4; ++_i)                                            \
        _Pragma("unroll")                                                     \
        for (int _n = 0; _n < 4; ++_n)                                        \
            acc[(MH) * 4 + _i][_n] = __builtin_amdgcn_mfma_f32_16x16x32_bf16( \
                av[_i], bv[_n], acc[(MH) * 4 + _i][_n], 0, 0, 0);             \
    __builtin_amdgcn_s_setprio(0);                                            \
} while (0)

#define GATE4() asm volatile("s_waitcnt vmcnt(4)" ::: "memory")
#define GATE0() asm volatile("s_waitcnt vmcnt(0)" ::: "memory")
#define BAR() do { __builtin_amdgcn_s_barrier(); __builtin_amdgcn_sched_barrier(0); } while (0)

    const int NT = K >> 6;   // K-tiles of 64 (K=1024 -> 16)

    bf16x8 a0[4], a1[4], a2[4], a3[4], b0[4], b1[4];

    // prologue: stage tile 0 (issue order u0,u1,u2,u3)
    STAGEU(0, 0, 0); STAGEU(0, 1, 0); STAGEU(0, 2, 0); STAGEU(0, 3, 0);

    for (int t = 0; t < NT - 1; ++t) {
        const int cur = t & 1, nxt = cur ^ 1;
        const char* pA = &lds[cur][0][0] + aoff;
        const char* pB = &lds[cur][1][0] + boff;
        // gate #1: units 0,1 of tile t landed for all waves
        GATE4(); BAR();
        LOAD4(a0, pA, 0);          // A MH0 KS0
        LOAD4(b0, pB, 0);          // B KS0
        LOAD4(a1, pA, 2048);       // A MH1 KS0
        STAGEU(nxt, 0, t + 1); STAGEU(nxt, 1, t + 1);
        // gate #2: units 2,3 of tile t landed (4 newer loads stay in flight)
        GATE4(); BAR();
        CL16(a0, b0, 0);           // KS0 reads drain under barrier-wait + this
        LOAD4(a2, pA, 16384);      // A MH0 KS1
        LOAD4(b1, pB, 16384);      // B KS1
        STAGEU(nxt, 2, t + 1); STAGEU(nxt, 3, t + 1);
        CL16(a1, b0, 1);           // KS1 reads drain under this
        LOAD4(a3, pA, 18432);      // A MH1 KS1
        CL16(a2, b1, 0);
        CL16(a3, b1, 1);
        // all reads of buf[cur] are register-consumed (in-order) before the
        // next iteration's barrier -> safe to overwrite buf[cur] there
    }
    {   // peeled last tile: no staging
        const int cur = (NT - 1) & 1;
        const char* pA = &lds[cur][0][0] + aoff;
        const char* pB = &lds[cur][1][0] + boff;
        GATE4(); BAR();
        LOAD4(a0, pA, 0);
        LOAD4(b0, pB, 0);
        LOAD4(a1, pA, 2048);
        GATE0(); BAR();            // only units 2,3 remain outstanding
        CL16(a0, b0, 0);
        LOAD4(a2, pA, 16384);
        LOAD4(b1, pB, 16384);
        CL16(a1, b0, 1);
        LOAD4(a3, pA, 18432);
        CL16(a2, b1, 0);
        CL16(a3, b1, 1);
    }

    // epilogue: bias + exp + 64-col row partials + atomic (verified r1-r4)
    float fbv[4], bbv[4];
#pragma unroll
    for (int nf = 0; nf < 4; ++nf) {
        const int v = bn * 256 + wn * 64 + nf * 16 + (lane & 15);
        fbv[nf] = fb[v]; bbv[nf] = bb[v];
    }
#pragma unroll
    for (int mf = 0; mf < 8; ++mf) {
#pragma unroll
        for (int j = 0; j < 4; ++j) {
            const int m = bm * 256 + wm * 128 + mf * 16 + ((lane >> 4) << 2) + j;
            if (m >= M) continue;   // uniform within each 16-lane shuffle group
            const bool isf = m < Nf;
            float ps = 0.f;
#pragma unroll
            for (int nf = 0; nf < 4; ++nf) {
                const float logit = acc[mf][nf][j] + (isf ? fbv[nf] : bbv[nf]);
                ps += exp2f(logit * LOG2E);
            }
#pragma unroll
            for (int s = 1; s < 16; s <<= 1) ps += __shfl_xor(ps, s);
            if ((lane & 15) == 0) atomicAdd(&S[m], ps);
        }
    }
#undef STAGEU
#undef LOAD4
#undef CL16
#undef GATE4
#undef GATE0
#undef BAR
}

// ---------------- fallback (ws too small for Wb): simple 128^2, in-stage conv ----------------
__global__ __launch_bounds__(256, 2)
void gemm_lse_fb(const __hip_bfloat16* __restrict__ A, const float* __restrict__ Bf,
                 const float* __restrict__ fb, const float* __restrict__ bb,
                 float* __restrict__ S, const int* __restrict__ hdr, int K) {
    const int M = hdr[0], Nf = hdr[1];
    const int bm = blockIdx.y, bn = blockIdx.x;
    if (bm * 128 >= M) return;
    __shared__ __align__(16) char lA[8192];
    __shared__ __align__(16) char lB[8192];
    const int tid = threadIdx.x, wid = tid >> 6, lane = tid & 63;
    const int wm = wid >> 1, wn = wid & 1;
    f32x4 acc[4][4];
#pragma unroll
    for (int i = 0; i < 4; ++i)
#pragma unroll
        for (int j = 0; j < 4; ++j) acc[i][j] = (f32x4)0.f;
    const char* gA = (const char*)A + (size_t)bm * 128 * K * 2;
    const int Kb = K * 2;
    int srow[2], skg[2];
#pragma unroll
    for (int j = 0; j < 2; ++j) {
        const int i = j * 256 + tid;
        srow[j] = ((i >> 6) << 4) | (i & 15);
        skg[j] = (i >> 4) & 3;
    }
    for (int kt = 0; kt < (K >> 5); ++kt) {
        __syncthreads();
#pragma unroll
        for (int j = 0; j < 2; ++j) {
            const int i = j * 256 + tid;
            __builtin_amdgcn_global_load_lds(
                (const AS1 uint32_t*)(gA + (size_t)srow[j] * Kb + (kt << 6) + skg[j] * 16),
                (AS3 uint32_t*)(lA + i * 16), 16, 0, 0);
            const float* src = Bf + (size_t)(bn * 128 + srow[j]) * K + (kt << 5) + skg[j] * 8;
            float4 v0 = *(const float4*)src, v1 = *(const float4*)(src + 4);
            union { __hip_bfloat16 h[8]; int4 i4; } u;
            u.h[0] = __float2bfloat16(v0.x); u.h[1] = __float2bfloat16(v0.y);
            u.h[2] = __float2bfloat16(v0.z); u.h[3] = __float2bfloat16(v0.w);
            u.h[4] = __float2bfloat16(v1.x); u.h[5] = __float2bfloat16(v1.y);
            u.h[6] = __float2bfloat16(v1.z); u.h[7] = __float2bfloat16(v1.w);
            *(int4*)(lB + i * 16) = u.i4;
        }
        __syncthreads();
        bf16x8 a[4], b[4];
        const char* pa = lA + (lane << 4);
        const char* pb = lB + (lane << 4);
#pragma unroll
        for (int mf = 0; mf < 4; ++mf) a[mf] = *(const bf16x8*)(pa + ((wm * 4 + mf) << 10));
#pragma unroll
        for (int nf = 0; nf < 4; ++nf) b[nf] = *(const bf16x8*)(pb + ((wn * 4 + nf) << 10));
#pragma unroll
        for (int mf = 0; mf < 4; ++mf)
#pragma unroll
            for (int nf = 0; nf < 4; ++nf)
                acc[mf][nf] = __builtin_amdgcn_mfma_f32_16x16x32_bf16(a[mf], b[nf], acc[mf][nf], 0, 0, 0);
    }
    float fbv[4], bbv[4];
#pragma unroll
    for (int nf = 0; nf < 4; ++nf) {
        int v = bn * 128 + wn * 64 + nf * 16 + (lane & 15);
        fbv[nf] = fb[v]; bbv[nf] = bb[v];
    }
#pragma unroll
    for (int mf = 0; mf < 4; ++mf) {
#pragma unroll
        for (int j = 0; j < 4; ++j) {
            int m = bm * 128 + wm * 64 + mf * 16 + (lane >> 4) * 4 + j;
            if (m >= M) continue;
            const bool isf = m < Nf;
            float ps = 0.f;
#pragma unroll
            for (int nf = 0; nf < 4; ++nf) {
                float logit = acc[mf][nf][j] + (isf ? fbv[nf] : bbv[nf]);
                ps += exp2f(logit * LOG2E);
            }
#pragma unroll
            for (int s = 1; s < 16; s <<= 1) ps += __shfl_xor(ps, s);
            if ((lane & 15) == 0) atomicAdd(&S[m], ps);
        }
    }
}

// ---------------- gold logits (exact f32) ----------------
__global__ void gold_kernel(const float* __restrict__ hs,
                            const float* __restrict__ W,
                            const float* __restrict__ fb,
                            const float* __restrict__ bb,
                            const int* __restrict__ row_ctx,
                            const int* __restrict__ row_tok,
                            const int* __restrict__ hdr,
                            float* __restrict__ goldv, int D2, int D) {
    const int m = blockIdx.x;
    const int M = hdr[0];
    if (m >= M) return;
    const int Nf = hdr[1];
    const int ctx = row_ctx[m], tok = row_tok[m];
    const float4* h = (const float4*)(hs + (size_t)ctx * D2 + (m < Nf ? 0 : D));
    const float4* w = (const float4*)(W + (size_t)tok * D);
    float s = 0.f;
    for (int i = threadIdx.x; i < D / 4; i += blockDim.x) {
        float4 a = h[i], b = w[i];
        s += a.x * b.x + a.y * b.y + a.z * b.z + a.w * b.w;
    }
#pragma unroll
    for (int d = 1; d < 64; d <<= 1) s += __shfl_xor(s, d);
    __shared__ float wsum[4];
    const int wid = threadIdx.x >> 6, lane = threadIdx.x & 63;
    if (lane == 0) wsum[wid] = s;
    __syncthreads();
    if (threadIdx.x == 0) {
        float tot = wsum[0] + wsum[1] + wsum[2] + wsum[3];
        tot += (m < Nf ? fb[tok] : bb[tok]);
        goldv[m] = tot;
    }
}

// ---------------- final reduce ----------------
__global__ void final_kernel(const float* __restrict__ S,
                             const float* __restrict__ goldv,
                             const int* __restrict__ hdr,
                             const float* __restrict__ fhdr,
                             float* __restrict__ out) {
    const int M = hdr[0];
    float s = 0.f;
    for (int m = threadIdx.x; m < M; m += blockDim.x)
        s += logf(S[m]) - goldv[m];
#pragma unroll
    for (int d = 1; d < 64; d <<= 1) s += __shfl_xor(s, d);
    __shared__ float wsum[4];
    const int wid = threadIdx.x >> 6, lane = threadIdx.x & 63;
    if (lane == 0) wsum[wid] = s;
    __syncthreads();
    if (threadIdx.x == 0)
        out[0] = (wsum[0] + wsum[1] + wsum[2] + wsum[3]) / fhdr[0];
}

extern "C" void kernel_launch(void* const* d_in, const int* in_sizes, int n_in,
                              void* d_out, int out_size, void* d_ws, size_t ws_size,
                              hipStream_t stream) {
    const float* hs  = (const float*)d_in[0];
    const float* W   = (const float*)d_in[1];
    const float* fb  = (const float*)d_in[2];
    const float* bb  = (const float*)d_in[3];
    const int* sent  = (const int*)d_in[4];
    const int* bs    = (const int*)d_in[5];
    const int total  = in_sizes[4];
    const int T      = in_sizes[5];
    const int V      = in_sizes[2];
    const int D      = in_sizes[1] / V;
    const int D2     = in_sizes[0] / total;
    const int Mcap   = ((2 * total) + 255) & ~255;   // 256-aligned upper bound
    const int MT     = Mcap / 256;
    const int NN     = V / 256;

    char* p = (char*)d_ws;
    int*   hdr     = (int*)p;            p += 256;
    float* fhdr    = (float*)p;          p += 256;
    int*   row_ctx = (int*)p;            p += (size_t)Mcap * 4;
    int*   row_tok = (int*)p;            p += (size_t)Mcap * 4;
    float* S       = (float*)p;          p += (size_t)Mcap * 4;
    float* goldv   = (float*)p;          p += (size_t)Mcap * 4;
    __hip_bfloat16* Hc = (__hip_bfloat16*)p; p += (size_t)Mcap * D * 2;
    __hip_bfloat16* Wb = (__hip_bfloat16*)p;
    const size_t need_wb = (size_t)(p - (char*)d_ws) + (size_t)V * D * 2;

    prep_kernel<<<1, 256, 0, stream>>>(bs, T, sent, hdr, fhdr, row_ctx, row_tok);
    gather_kernel<<<Mcap, 256, 0, stream>>>(hs, row_ctx, hdr, Hc, S, D2, D);

    if (ws_size >= need_wb) {
        long n4 = (long)V * D / 4;
        wconv_kernel<<<(int)((n4 + 255) / 256), 256, 0, stream>>>(W, Wb, n4);
        gemm_lse_256<<<NN * MT, 512, 0, stream>>>(Hc, Wb, fb, bb, S, hdr, D, MT);
    } else {
        dim3 grid(V / 128, Mcap / 128);
        gemm_lse_fb<<<grid, 256, 0, stream>>>(Hc, W, fb, bb, S, hdr, D);
    }

    gold_kernel<<<Mcap, 256, 0, stream>>>(hs, W, fb, bb, row_ctx, row_tok, hdr, goldv, D2, D);
    final_kernel<<<1, 256, 0, stream>>>(S, goldv, hdr, fhdr, (float*)d_out);
}

// Round 6
// 346.032 us; speedup vs baseline: 1.4044x; 1.4044x over previous
//
#include <hip/hip_runtime.h>
#include <hip/hip_bf16.h>
#include <stdint.h>

typedef __bf16 bf16x8 __attribute__((ext_vector_type(8)));
typedef float f32x4 __attribute__((ext_vector_type(4)));

#define LOG2E 1.4426950408889634f
#define AS1 __attribute__((address_space(1)))
#define AS3 __attribute__((address_space(3)))

// Operand layout ("tile-frag order"): for a row-panel of R rows (R=128 for A,
// 256 for B), data stored as [k-tile t (32 k)][frag f (16 rows)][lane l 0..63]
// x 16B, where chunk (f,l) holds row f*16+(l&15), k = t*32 + (l>>4)*8.
// This makes (a) GEMM staging perfectly sequential (base + tid*16), and
// (b) LDS fragment reads contiguous 1KB wave accesses (conflict-free),
// with LDS dest linear (rule #21 satisfied on both sides by construction).

// ---------------- prep: build indices from batch_sizes ----------------
__global__ void prep_kernel(const int* __restrict__ bs, int T,
                            const int* __restrict__ sentences,
                            int* __restrict__ hdr, float* __restrict__ fhdr,
                            int* __restrict__ row_ctx, int* __restrict__ row_tok) {
    __shared__ int off[1025];
    if (threadIdx.x == 0) {
        int acc = 0; off[0] = 0;
        for (int t = 0; t < T; ++t) { acc += bs[t]; off[t + 1] = acc; }
    }
    __syncthreads();
    const int total = off[T];
    const int Nf = total - off[1];
    const int Nb = total - off[2];
    for (int t = 1; t < T; ++t) {
        int start = off[t] - off[1];
        int cnt = off[t + 1] - off[t];
        for (int p = threadIdx.x; p < cnt; p += blockDim.x) {
            row_ctx[start + p] = off[t - 1] + p;
            row_tok[start + p] = sentences[off[t] + p];
        }
    }
    for (int i = 1; i < T - 1; ++i) {
        int start = Nf + off[i + 1] - off[2];
        int cnt = off[i + 2] - off[i + 1];
        for (int p = threadIdx.x; p < cnt; p += blockDim.x) {
            row_ctx[start + p] = off[i + 1] + p;
            row_tok[start + p] = sentences[off[i] + p];
        }
    }
    if (threadIdx.x == 0) {
        hdr[0] = Nf + Nb;
        hdr[1] = Nf;
        int bs0 = off[1];
        int bsl = off[T] - off[T - 1];
        fhdr[0] = (float)(2 * total - bs0 - bsl);
    }
}

__device__ __forceinline__ int4 cvt8(float4 v0, float4 v1) {
    union { __hip_bfloat16 h[8]; int4 i4; } u;
    u.h[0] = __float2bfloat16(v0.x); u.h[1] = __float2bfloat16(v0.y);
    u.h[2] = __float2bfloat16(v0.z); u.h[3] = __float2bfloat16(v0.w);
    u.h[4] = __float2bfloat16(v1.x); u.h[5] = __float2bfloat16(v1.y);
    u.h[6] = __float2bfloat16(v1.z); u.h[7] = __float2bfloat16(v1.w);
    return u.i4;
}

// ---------------- W f32 -> bf16 in tile-frag order ----------------
// grid: (V/256)*16 blocks x 512 threads; block (p = bx>>4, f = bx&15)
__global__ void wconv_kernel(const float* __restrict__ W,
                             __hip_bfloat16* __restrict__ Wb, int K) {
    const int p = blockIdx.x >> 4, f = blockIdx.x & 15;
    char* dst = (char*)Wb + ((size_t)p * 256 + (size_t)f * 0) * K * 2  // panel base
                + (size_t)p * 0;  // (computed below properly)
    char* panel = (char*)Wb + (size_t)p * 256 * K * 2;
    const int nch = 2 * K;   // 16 rows * K * 2B / 16B
    for (int c = threadIdx.x; c < nch; c += 512) {
        const int t = c >> 6, l = c & 63;
        const int row = p * 256 + f * 16 + (l & 15);
        const int k = t * 32 + ((l >> 4) << 3);
        const float4* src = (const float4*)(W + (size_t)row * K + k);
        *(int4*)(panel + (size_t)t * 16384 + f * 1024 + l * 16) = cvt8(src[0], src[1]);
    }
    (void)dst;
}

// ---------------- gather context rows -> bf16 tile-frag order, zero S -------
// grid: (Mcap/128)*8 blocks x 512 threads; block (p = bx>>3, f = bx&7)
__global__ void gather_kernel(const float* __restrict__ hs,
                              const int* __restrict__ row_ctx,
                              const int* __restrict__ hdr,
                              __hip_bfloat16* __restrict__ Hc,
                              float* __restrict__ S, int D2, int K) {
    const int p = blockIdx.x >> 3, f = blockIdx.x & 7;
    const int M = hdr[0], Nf = hdr[1];
    if (threadIdx.x < 16) S[p * 128 + f * 16 + threadIdx.x] = 0.f;
    char* panel = (char*)Hc + (size_t)p * 128 * K * 2;
    const int nch = 2 * K;
    for (int c = threadIdx.x; c < nch; c += 512) {
        const int t = c >> 6, l = c & 63;
        const int row = p * 128 + f * 16 + (l & 15);
        char* d = panel + (size_t)t * 8192 + f * 1024 + l * 16;
        if (row >= M) {
            int4 z; z.x = z.y = z.z = z.w = 0;
            *(int4*)d = z;
        } else {
            const int ctx = row_ctx[row];
            const int k = t * 32 + ((l >> 4) << 3);
            const float4* src = (const float4*)(hs + (size_t)ctx * D2 + (row < Nf ? 0 : K) + k);
            *(int4*)d = cvt8(src[0], src[1]);
        }
    }
}

// ---------------- main 128x256 / BK=32 / 8-wave GEMM + sum-exp ----------------
// 2 blocks/CU (4 waves/SIMD TLP), sequential staging, counted vmcnt gate.
template <bool CONVB>
__global__ __launch_bounds__(512, 4)
void gemm_lse(const __hip_bfloat16* __restrict__ A,
              const void* __restrict__ Bvoid,
              const float* __restrict__ fb,
              const float* __restrict__ bb,
              float* __restrict__ S,
              const int* __restrict__ hdr, int K, int MT) {
    const int M = hdr[0], Nf = hdr[1];

    // XCD-aware bijective swizzle (m204), bm-fastest (r2: FETCH -48%).
    const int nwg = gridDim.x, orig = blockIdx.x;
    const int q = nwg >> 3, rr = nwg & 7;
    const int xcd = orig & 7, i8 = orig >> 3;
    const int wgid = (xcd < rr ? xcd * (q + 1) : rr * (q + 1) + (xcd - rr) * q) + i8;
    const int bm = wgid % MT, bn = wgid / MT;
    if (bm * 128 >= M) return;

    __shared__ __align__(16) char lA[2][8192];
    __shared__ __align__(16) char lB[2][16384];

    const int tid = threadIdx.x, lane = tid & 63, wid = tid >> 6;
    const int wm = wid >> 2, wn = wid & 3;     // 2M x 4N waves, each 64x64 out

    f32x4 acc[4][4];
#pragma unroll
    for (int i = 0; i < 4; ++i)
#pragma unroll
        for (int j = 0; j < 4; ++j) acc[i][j] = (f32x4)0.f;

    const char* Ab = (const char*)A + (size_t)bm * 128 * K * 2;  // panel, tile-frag order
    const __hip_bfloat16* Bb = (const __hip_bfloat16*)Bvoid;
    const float* Bf = (const float*)Bvoid;
    const char* Bp = (const char*)Bb + (size_t)bn * 256 * K * 2;
    const int sd = tid << 4;

    // fragment read bases: contiguous 1KB per wave per frag (conflict-free)
    const int ao = (wm << 12) + (lane << 4);   // + mf*1024
    const int bo = (wn << 12) + (lane << 4);   // + nf*1024

#define GLDS(src, dst) __builtin_amdgcn_global_load_lds(                      \
        (const AS1 uint32_t*)(src), (AS3 uint32_t*)(dst), 16, 0, 0)

#define STAGE(buf, t) do {                                                    \
    GLDS(Ab + (size_t)(t) * 8192 + sd, lA[buf] + sd);                         \
    GLDS(Bp + (size_t)(t) * 16384 + sd, lB[buf] + sd);                        \
    GLDS(Bp + (size_t)(t) * 16384 + 8192 + sd, lB[buf] + 8192 + sd);          \
} while (0)

#define COMPUTE(buf) do {                                                     \
    bf16x8 a[4], b[4];                                                        \
    _Pragma("unroll")                                                         \
    for (int mf = 0; mf < 4; ++mf) a[mf] = *(const bf16x8*)(lA[buf] + ao + (mf << 10)); \
    _Pragma("unroll")                                                         \
    for (int nf = 0; nf < 4; ++nf) b[nf] = *(const bf16x8*)(lB[buf] + bo + (nf << 10)); \
    __builtin_amdgcn_s_setprio(1);                                            \
    _Pragma("unroll")                                                         \
    for (int mf = 0; mf < 4; ++mf)                                            \
        _Pragma("unroll")                                                     \
        for (int nf = 0; nf < 4; ++nf)                                        \
            acc[mf][nf] = __builtin_amdgcn_mfma_f32_16x16x32_bf16(            \
                a[mf], b[nf], acc[mf][nf], 0, 0, 0);                          \
    __builtin_amdgcn_s_setprio(0);                                            \
} while (0)

#define BAR() do { __builtin_amdgcn_s_barrier(); __builtin_amdgcn_sched_barrier(0); } while (0)

    const int NT = K >> 5;   // 32-k tiles (K=1024 -> 32)

    if constexpr (!CONVB) {
        STAGE(0, 0);
        for (int t = 0; t < NT - 1; ++t) {
            STAGE((t + 1) & 1, t + 1);                     // 3 loads in flight
            asm volatile("s_waitcnt vmcnt(3)" ::: "memory");  // tile t landed
            BAR();                                          // ... for all waves
            COMPUTE(t & 1);
            BAR();   // all waves done reading buf[t&1] before t+1 stages it
        }
        asm volatile("s_waitcnt vmcnt(0)" ::: "memory");
        BAR();
        COMPUTE((NT - 1) & 1);
    } else {
        // fallback: W stays f32; B converted in-stage via ds_write (slow path)
        for (int t = 0; t < NT; ++t) {
            __syncthreads();
            GLDS(Ab + (size_t)t * 8192 + sd, lA[0] + sd);
#pragma unroll
            for (int j = 0; j < 2; ++j) {
                const int c = j * 512 + tid;
                const int f = c >> 6, l = c & 63;
                const int row = bn * 256 + f * 16 + (l & 15);
                const int k = t * 32 + ((l >> 4) << 3);
                const float4* src = (const float4*)(Bf + (size_t)row * K + k);
                *(int4*)(lB[0] + c * 16) = cvt8(src[0], src[1]);
            }
            __syncthreads();
            COMPUTE(0);
        }
    }

    // epilogue: bias + exp + 64-col row partials + atomic (verified r1-r5)
    float fbv[4], bbv[4];
#pragma unroll
    for (int nf = 0; nf < 4; ++nf) {
        const int v = bn * 256 + wn * 64 + nf * 16 + (lane & 15);
        fbv[nf] = fb[v]; bbv[nf] = bb[v];
    }
#pragma unroll
    for (int mf = 0; mf < 4; ++mf) {
#pragma unroll
        for (int j = 0; j < 4; ++j) {
            const int m = bm * 128 + wm * 64 + mf * 16 + ((lane >> 4) << 2) + j;
            if (m >= M) continue;   // uniform within each 16-lane shuffle group
            const bool isf = m < Nf;
            float ps = 0.f;
#pragma unroll
            for (int nf = 0; nf < 4; ++nf) {
                const float logit = acc[mf][nf][j] + (isf ? fbv[nf] : bbv[nf]);
                ps += exp2f(logit * LOG2E);
            }
#pragma unroll
            for (int s = 1; s < 16; s <<= 1) ps += __shfl_xor(ps, s);
            if ((lane & 15) == 0) atomicAdd(&S[m], ps);
        }
    }
#undef GLDS
#undef STAGE
#undef COMPUTE
#undef BAR
}

// ---------------- gold logits (exact f32) ----------------
__global__ void gold_kernel(const float* __restrict__ hs,
                            const float* __restrict__ W,
                            const float* __restrict__ fb,
                            const float* __restrict__ bb,
                            const int* __restrict__ row_ctx,
                            const int* __restrict__ row_tok,
                            const int* __restrict__ hdr,
                            float* __restrict__ goldv, int D2, int D) {
    const int m = blockIdx.x;
    const int M = hdr[0];
    if (m >= M) return;
    const int Nf = hdr[1];
    const int ctx = row_ctx[m], tok = row_tok[m];
    const float4* h = (const float4*)(hs + (size_t)ctx * D2 + (m < Nf ? 0 : D));
    const float4* w = (const float4*)(W + (size_t)tok * D);
    float s = 0.f;
    for (int i = threadIdx.x; i < D / 4; i += blockDim.x) {
        float4 a = h[i], b = w[i];
        s += a.x * b.x + a.y * b.y + a.z * b.z + a.w * b.w;
    }
#pragma unroll
    for (int d = 1; d < 64; d <<= 1) s += __shfl_xor(s, d);
    __shared__ float wsum[4];
    const int wid = threadIdx.x >> 6, lane = threadIdx.x & 63;
    if (lane == 0) wsum[wid] = s;
    __syncthreads();
    if (threadIdx.x == 0) {
        float tot = wsum[0] + wsum[1] + wsum[2] + wsum[3];
        tot += (m < Nf ? fb[tok] : bb[tok]);
        goldv[m] = tot;
    }
}

// ---------------- final reduce ----------------
__global__ void final_kernel(const float* __restrict__ S,
                             const float* __restrict__ goldv,
                             const int* __restrict__ hdr,
                             const float* __restrict__ fhdr,
                             float* __restrict__ out) {
    const int M = hdr[0];
    float s = 0.f;
    for (int m = threadIdx.x; m < M; m += blockDim.x)
        s += logf(S[m]) - goldv[m];
#pragma unroll
    for (int d = 1; d < 64; d <<= 1) s += __shfl_xor(s, d);
    __shared__ float wsum[4];
    const int wid = threadIdx.x >> 6, lane = threadIdx.x & 63;
    if (lane == 0) wsum[wid] = s;
    __syncthreads();
    if (threadIdx.x == 0)
        out[0] = (wsum[0] + wsum[1] + wsum[2] + wsum[3]) / fhdr[0];
}

extern "C" void kernel_launch(void* const* d_in, const int* in_sizes, int n_in,
                              void* d_out, int out_size, void* d_ws, size_t ws_size,
                              hipStream_t stream) {
    const float* hs  = (const float*)d_in[0];
    const float* W   = (const float*)d_in[1];
    const float* fb  = (const float*)d_in[2];
    const float* bb  = (const float*)d_in[3];
    const int* sent  = (const int*)d_in[4];
    const int* bs    = (const int*)d_in[5];
    const int total  = in_sizes[4];
    const int T      = in_sizes[5];
    const int V      = in_sizes[2];
    const int D      = in_sizes[1] / V;
    const int D2     = in_sizes[0] / total;
    const int Mcap   = ((2 * total) + 127) & ~127;   // 128-aligned upper bound
    const int MT     = Mcap / 128;
    const int NN     = V / 256;

    char* p = (char*)d_ws;
    int*   hdr     = (int*)p;            p += 256;
    float* fhdr    = (float*)p;          p += 256;
    int*   row_ctx = (int*)p;            p += (size_t)Mcap * 4;
    int*   row_tok = (int*)p;            p += (size_t)Mcap * 4;
    float* S       = (float*)p;          p += (size_t)Mcap * 4;
    float* goldv   = (float*)p;          p += (size_t)Mcap * 4;
    __hip_bfloat16* Hc = (__hip_bfloat16*)p; p += (size_t)Mcap * D * 2;
    __hip_bfloat16* Wb = (__hip_bfloat16*)p;
    const size_t need_wb = (size_t)(p - (char*)d_ws) + (size_t)V * D * 2;

    prep_kernel<<<1, 256, 0, stream>>>(bs, T, sent, hdr, fhdr, row_ctx, row_tok);
    gather_kernel<<<(Mcap / 128) * 8, 512, 0, stream>>>(hs, row_ctx, hdr, Hc, S, D2, D);

    if (ws_size >= need_wb) {
        wconv_kernel<<<(V / 256) * 16, 512, 0, stream>>>(W, Wb, D);
        gemm_lse<false><<<NN * MT, 512, 0, stream>>>(Hc, (const void*)Wb, fb, bb, S, hdr, D, MT);
    } else {
        gemm_lse<true><<<NN * MT, 512, 0, stream>>>(Hc, (const void*)W, fb, bb, S, hdr, D, MT);
    }

    gold_kernel<<<Mcap, 256, 0, stream>>>(hs, W, fb, bb, row_ctx, row_tok, hdr, goldv, D2, D);
    final_kernel<<<1, 256, 0, stream>>>(S, goldv, hdr, fhdr, (float*)d_out);
}